// Round 3
// baseline (279.428 us; speedup 1.0000x reference)
//
#include <hip/hip_runtime.h>
#include <hip/hip_bf16.h>

using bf16 = __hip_bfloat16;
typedef __attribute__((ext_vector_type(8))) short short8;
typedef __attribute__((ext_vector_type(4))) float float4v;

#define N_NODES 40962
#define N_EDGES 245760
#define NP      41024      // 641*64, padded node count
#define KG      10
#define SCAN_B  256
#define NBLK    ((NP + SCAN_B - 1) / SCAN_B)   // 161
#define GRIDF   (NP / 16)                      // 2564 fused blocks (16 rows each)

// fused prep grid partition
#define CVT_V   (N_NODES * 64 / 8)             // 327696 vectors of 8
#define CVT_BLK ((CVT_V + 255) / 256)          // 1281
#define W3_BLK  (N_EDGES / 256)                // 960
#define PACK_N  (64 * 704 + 2 * 128 * 704)     // 225280
#define PACK_BLK (PACK_N / 256)                // 880

// k-dim ordering (shared by z LDS stores, x/h frag layout, and B pack):
//   k in [0,512):   cin = k>>3,        kg = k&7      (k = cin*8+kg)
//   k in [512,640): cin = (k-512)>>1,  kg = 8+((k-512)&1)
//   k in [640,704): root row cin = k-640
// Frag layouts (memory layout == MFMA fragment layout):
//   Xf/hf[c][node][32] c=0..1   : element t -> cin = c*32+t (root part)
//   Bp[((n*22+kc)*64+lane)*8+j] : col = n*16+(lane&15), k = kc*32+(lane>>4)*8+j
// CSR-ordered edge data: csr_src[pos]=source node; wc1/wcs/wc2[pos*5 u32] =
// packed bf16 weight pairs. Weight reads in the gathers are sequential per
// node; only X[src]/hf[src] remain random (L2/L3-resident).
//
// LDS z tile (fused kernels): z[kc][16 rows][*], row stride ZRS=40 elems
// (80 B), kc stride ZKS=648 elems (1296 B). Both the gather-phase write
// pattern (chunk=lane>>2) and GEMM-phase read pattern (row=lane&15) spread
// 8 lanes per 4-bank group -> 8-cycle LDS floor, conflict-free.
#define ZRS  40
#define ZKS  648
#define ZSZE 12960   // max index 12944 (chunk 19, row 15), padded to 16-mult

// flag[0] == 1 -> float inputs/outputs are f32 ; 0 -> bf16
__device__ __forceinline__ float ldf(const void* p, size_t i, int isf32) {
    return isf32 ? ((const float*)p)[i] : __bfloat162float(((const bf16*)p)[i]);
}
__device__ __forceinline__ float blo(unsigned u) { return __uint_as_float(u << 16); }
__device__ __forceinline__ float bhi(unsigned u) { return __uint_as_float(u & 0xffff0000u); }
__device__ __forceinline__ unsigned pk2(float a, float b) {
    union { bf16 h[2]; unsigned u; } t;
    t.h[0] = __float2bfloat16(a);
    t.h[1] = __float2bfloat16(b);
    return t.u;
}
__device__ __forceinline__ int rfl(int v) { return __builtin_amdgcn_readfirstlane(v); }

// ---------------- fused dtype detector + degree count ----------------
__global__ void k_detect_count(const void* x, const int* __restrict__ ei,
                               int* __restrict__ flag, int* __restrict__ deg) {
    if (blockIdx.x == 0) {
        __shared__ int huge_c, zero_even;
        if (threadIdx.x == 0) { huge_c = 0; zero_even = 0; }
        __syncthreads();
        const bf16* xb = (const bf16*)x;
        int lh = 0, lz = 0;
        for (int i = threadIdx.x; i < 8192; i += 256) {
            float v = __bfloat162float(xb[i]);
            if (!(fabsf(v) <= 1e4f)) lh++;
            if ((i & 1) == 0 && v == 0.0f) lz++;
        }
        atomicAdd(&huge_c, lh);
        atomicAdd(&zero_even, lz);
        __syncthreads();
        if (threadIdx.x == 0) flag[0] = (huge_c > 0 || zero_even > 3000) ? 1 : 0;
    } else {
        int e = (blockIdx.x - 1) * 256 + threadIdx.x;
        if (e < N_EDGES) atomicAdd(&deg[ei[N_EDGES + e]], 1);
    }
}

// ---------------- scan stage 1: block-local exclusive + block sums ----------------
__global__ void k_scan1(const int* __restrict__ deg, int* __restrict__ offs,
                        int* __restrict__ bsum) {
    __shared__ int buf[SCAN_B];
    int t = threadIdx.x, b = blockIdx.x;
    int i = b * SCAN_B + t;
    int v = (i < NP) ? deg[i] : 0;
    buf[t] = v;
    __syncthreads();
    for (int off = 1; off < SCAN_B; off <<= 1) {
        int a = (t >= off) ? buf[t - off] : 0;
        __syncthreads();
        buf[t] += a;
        __syncthreads();
    }
    if (i < NP) offs[i] = buf[t] - v;
    if (t == SCAN_B - 1) bsum[b] = buf[t];
}

// ---------------- scan stage 2 (merged): each block re-scans bsum locally ----------------
__global__ void k_scan3m(int* __restrict__ offs, const int* __restrict__ bsum,
                         const int* __restrict__ deg, int* __restrict__ cur,
                         float* __restrict__ invdeg) {
    __shared__ int buf[256];
    int t = threadIdx.x, b = blockIdx.x;
    int v = (t < NBLK) ? bsum[t] : 0;
    buf[t] = v;
    __syncthreads();
    for (int off = 1; off < 256; off <<= 1) {
        int a = (t >= off) ? buf[t - off] : 0;
        __syncthreads();
        buf[t] += a;
        __syncthreads();
    }
    int bofs = (b > 0) ? buf[b - 1] : 0;
    int total = buf[NBLK - 1];
    int i = b * 256 + t;
    if (i < NP) {
        int o = offs[i] + bofs;
        offs[i] = o;
        cur[i] = o;
        int d = deg[i];
        invdeg[i] = 1.0f / (float)(d > 1 ? d : 1);
    }
    if (i == 0) offs[NP] = total;
}

// ---------------- CSR fill: pos per edge, src in CSR order ----------------
__global__ void k_fill(const int* __restrict__ ei, int* __restrict__ cur,
                       int* __restrict__ ep, int* __restrict__ csr_src) {
    int e = blockIdx.x * 256 + threadIdx.x;
    if (e < N_EDGES) {
        int pos = atomicAdd(&cur[ei[N_EDGES + e]], 1);
        ep[e] = pos;
        csr_src[pos] = ei[e];
    }
}

// ---------------- gaussian weights helper ----------------
__device__ __forceinline__ void gw_one(float p0, float p1, const void* mu,
                                       const void* sg, int f, float* out) {
#pragma unroll
    for (int k = 0; k < KG; k++) {
        float m0 = ldf(mu, 2 * k + 0, f), m1 = ldf(mu, 2 * k + 1, f);
        float s0 = ldf(sg, 2 * k + 0, f), s1 = ldf(sg, 2 * k + 1, f);
        float d0 = p0 - m0, d1 = p1 - m1;
        float t = -0.5f * (d0 * d0 / (1e-15f + s0 * s0) + d1 * d1 / (1e-15f + s1 * s1));
        out[k] = __expf(t);
    }
}

// ---------------- B pack in fragment order ----------------
__device__ __forceinline__ void pack_frag(const void* g, const void* root, int f,
                                          int idx, int Cout, bf16* Bp) {
    int j = idx & 7;
    int lane = (idx >> 3) & 63;
    int rem = idx >> 9;
    int kc = rem % 22;
    int n = rem / 22;
    int col = n * 16 + (lane & 15);
    int k = kc * 32 + (lane >> 4) * 8 + j;
    float v;
    if (k < 512) {
        int cin = k >> 3, kg = k & 7;
        v = ldf(g, (size_t)cin * (KG * Cout) + (size_t)kg * Cout + col, f);
    } else if (k < 640) {
        int jj = k - 512;
        int cin = jj >> 1, kg = 8 + (jj & 1);
        v = ldf(g, (size_t)cin * (KG * Cout) + (size_t)kg * Cout + col, f);
    } else {
        v = ldf(root, (size_t)(k - 640) * Cout + col, f);
    }
    Bp[idx] = __float2bfloat16(v);
}

// ---------------- fused prep: cvt x->Xf | w3 (CSR-order writes) | pack3 ---------
// NOTE: must run AFTER k_fill (reads ep[] for csr-order weight placement).
__global__ void k_prep_all(const void* __restrict__ x, const void* __restrict__ pseudo,
                           const void* mu1, const void* sg1, const void* mu2,
                           const void* sg2, const void* mus, const void* sgs,
                           const void* g1, const void* root1, const void* g2,
                           const void* root2, const void* gs, const void* roots,
                           const int* __restrict__ flag, const int* __restrict__ ep,
                           bf16* __restrict__ Xf, bf16* __restrict__ wc1,
                           bf16* __restrict__ wcs, bf16* __restrict__ wc2,
                           bf16* wt1p, bf16* wt2p, bf16* wtsp) {
    int b = blockIdx.x;
    int tid = threadIdx.x;
    int f = flag[0];
    if (b < CVT_BLK) {
        int i = b * 256 + tid;
        if (i < CVT_V) {
            int node = i >> 3, j = i & 7;   // covers x[node][j*8 .. j*8+8)
            uint4 u;
            if (f) {
                const float4* xf = (const float4*)x;
                float4 a = xf[2 * i], c = xf[2 * i + 1];
                union { bf16 t[8]; uint4 u; } tt;
                tt.t[0] = __float2bfloat16(a.x); tt.t[1] = __float2bfloat16(a.y);
                tt.t[2] = __float2bfloat16(a.z); tt.t[3] = __float2bfloat16(a.w);
                tt.t[4] = __float2bfloat16(c.x); tt.t[5] = __float2bfloat16(c.y);
                tt.t[6] = __float2bfloat16(c.z); tt.t[7] = __float2bfloat16(c.w);
                u = tt.u;
            } else {
                u = ((const uint4*)x)[i];
            }
            *(uint4*)(Xf + ((size_t)(j >> 2) * NP + node) * 32 + (j & 3) * 8) = u;
        }
    } else if (b < CVT_BLK + W3_BLK) {
        int e = (b - CVT_BLK) * 256 + tid;
        float p0 = ldf(pseudo, (size_t)e * 2 + 0, f);
        float p1 = ldf(pseudo, (size_t)e * 2 + 1, f);
        float o1[KG], o2[KG], os[KG];
        gw_one(p0, p1, mu1, sg1, f, o1);
        gw_one(p0, p1, mu2, sg2, f, o2);
        gw_one(p0, p1, mus, sgs, f, os);
        int pos = ep[e];
        unsigned* d1 = (unsigned*)wc1 + (size_t)pos * 5;
        d1[0] = pk2(o1[0], o1[1]); d1[1] = pk2(o1[2], o1[3]);
        d1[2] = pk2(o1[4], o1[5]); d1[3] = pk2(o1[6], o1[7]);
        d1[4] = pk2(o1[8], o1[9]);
        unsigned* ds = (unsigned*)wcs + (size_t)pos * 5;
        ds[0] = pk2(os[0], os[1]); ds[1] = pk2(os[2], os[3]);
        ds[2] = pk2(os[4], os[5]); ds[3] = pk2(os[6], os[7]);
        ds[4] = pk2(os[8], os[9]);
        unsigned* d2 = (unsigned*)wc2 + (size_t)pos * 5;
        d2[0] = pk2(o2[0], o2[1]); d2[1] = pk2(o2[2], o2[3]);
        d2[2] = pk2(o2[4], o2[5]); d2[3] = pk2(o2[6], o2[7]);
        d2[4] = pk2(o2[8], o2[9]);
    } else {
        int idx = (b - CVT_BLK - W3_BLK) * 256 + tid;
        if (idx < 64 * 704) {
            pack_frag(g1, root1, f, idx, 64, wt1p);
        } else if (idx < 64 * 704 + 128 * 704) {
            pack_frag(g2, root2, f, idx - 64 * 704, 128, wt2p);
        } else {
            pack_frag(gs, roots, f, idx - 64 * 704 - 128 * 704, 128, wtsp);
        }
    }
}

// X frag-layout read: cin = lane -> chunk lane>>5, t = lane&31
__device__ __forceinline__ float ldx_frag(const bf16* X, int src, int lane) {
    return __bfloat162float(X[((size_t)(lane >> 5) * NP + src) * 32 + (lane & 31)]);
}

__device__ __forceinline__ int clampe(int idx) {
    return idx > N_EDGES - 1 ? N_EDGES - 1 : idx;
}

// ---------------- z store into LDS tile (frag-indexed, conflict-free pads) ------
__device__ __forceinline__ void store_zlds(bf16* z, int r, int lane, const float* a,
                                           float inv) {
    union { bf16 h[8]; uint4 u; } p;
#pragma unroll
    for (int k = 0; k < 8; k++) p.h[k] = __float2bfloat16(a[k] * inv);
    *(uint4*)(z + (lane >> 2) * ZKS + r * ZRS + (lane & 3) * 8) = p.u;
    *(unsigned*)(z + (16 + (lane >> 4)) * ZKS + r * ZRS + (lane & 15) * 2) =
        pk2(a[8] * inv, a[9] * inv);
}

// ---------------- fused conv1: gather(x,w1)->LDS z + GEMM -> hf (relu) ----------
__global__ __launch_bounds__(256) void k_fused1(
    const int* __restrict__ offs, const int* __restrict__ csr_src,
    const bf16* __restrict__ wc1, const float* __restrict__ invdeg,
    const bf16* __restrict__ Xf, const bf16* __restrict__ wt1p,
    const void* __restrict__ b1, const int* __restrict__ flag,
    bf16* __restrict__ hf) {
    __shared__ bf16 zA[ZSZE];
    int lane = threadIdx.x & 63;
    int wave = threadIdx.x >> 6;
    int bid = blockIdx.x;
    const unsigned* wb = (const unsigned*)wc1;

    for (int i = 0; i < 4; i++) {
        int r = wave * 4 + i;
        int node = bid * 16 + r;
        float acc[KG];
#pragma unroll
        for (int k = 0; k < KG; k++) acc[k] = 0.0f;
        int beg = rfl(offs[node]);
        int end = rfl(offs[node + 1]);
        int cnt = end - beg;
        int sC = rfl(csr_src[clampe(beg + 2)]);
        float xv0 = ldx_frag(Xf, rfl(csr_src[clampe(beg + 0)]), lane);
        float xv1 = ldx_frag(Xf, rfl(csr_src[clampe(beg + 1)]), lane);
        const unsigned* wp0 = wb + (size_t)clampe(beg + 0) * 5;
        unsigned c0 = wp0[0], c1 = wp0[1], c2 = wp0[2], c3 = wp0[3], c4 = wp0[4];
        const unsigned* wp1 = wb + (size_t)clampe(beg + 1) * 5;
        unsigned n0 = wp1[0], n1 = wp1[1], n2 = wp1[2], n3 = wp1[3], n4 = wp1[4];
        for (int t = 0; t < cnt; ++t) {
            int sN = rfl(csr_src[clampe(beg + t + 3)]);
            float xv2 = ldx_frag(Xf, sC, lane);
            const unsigned* wp2 = wb + (size_t)clampe(beg + t + 2) * 5;
            unsigned m0 = wp2[0], m1 = wp2[1], m2 = wp2[2], m3 = wp2[3], m4 = wp2[4];
            acc[0] += blo(c0) * xv0; acc[1] += bhi(c0) * xv0;
            acc[2] += blo(c1) * xv0; acc[3] += bhi(c1) * xv0;
            acc[4] += blo(c2) * xv0; acc[5] += bhi(c2) * xv0;
            acc[6] += blo(c3) * xv0; acc[7] += bhi(c3) * xv0;
            acc[8] += blo(c4) * xv0; acc[9] += bhi(c4) * xv0;
            xv0 = xv1; xv1 = xv2; sC = sN;
            c0 = n0; c1 = n1; c2 = n2; c3 = n3; c4 = n4;
            n0 = m0; n1 = m1; n2 = m2; n3 = m3; n4 = m4;
        }
        store_zlds(zA, r, lane, acc, invdeg[node]);
    }
    __syncthreads();

    // GEMM: 16 rows x 64 cols; col-tile n = wave; A from LDS + Xf root rows
    int m = lane & 15, quad = lane >> 4;
    int row0 = bid * 16;
    float4v acc4 = (float4v){0.f, 0.f, 0.f, 0.f};
    const bf16* brow = wt1p + ((size_t)(wave * 22) * 64 + lane) * 8;
    const bf16* xrow = Xf + ((size_t)(row0 + m)) * 32 + quad * 8;
#pragma unroll
    for (int kc = 0; kc < 22; kc++) {
        short8 a = (kc < 20)
            ? *(const short8*)(zA + kc * ZKS + m * ZRS + quad * 8)
            : *(const short8*)(xrow + (size_t)(kc - 20) * NP * 32);
        short8 b = *(const short8*)(brow + (size_t)kc * 512);
        acc4 = __builtin_amdgcn_mfma_f32_16x16x32_bf16(a, b, acc4, 0, 0, 0);
    }
    int f = flag[0];
    int gcol = wave * 16 + m;
    float bv = ldf(b1, gcol, f);
#pragma unroll
    for (int r = 0; r < 4; r++) {
        int grow = row0 + quad * 4 + r;
        if (grow >= N_NODES) continue;
        float v = fmaxf(acc4[r] + bv, 0.f);
        hf[((size_t)(gcol >> 5) * NP + grow) * 32 + (gcol & 31)] = __float2bfloat16(v);
    }
}

// ---------------- fused conv2+shortcut: dual gather->LDS + 2 GEMMs -> out -------
__global__ __launch_bounds__(256) void k_fused2(
    const int* __restrict__ offs, const int* __restrict__ csr_src,
    const bf16* __restrict__ wc2, const bf16* __restrict__ wcs,
    const float* __restrict__ invdeg, const bf16* __restrict__ Xf,
    const bf16* __restrict__ hf, const bf16* __restrict__ wt2p,
    const bf16* __restrict__ wtsp, const void* __restrict__ b2,
    const void* __restrict__ bs, const int* __restrict__ flag,
    void* __restrict__ out) {
    __shared__ bf16 z2[ZSZE];
    __shared__ bf16 zs[ZSZE];
    int lane = threadIdx.x & 63;
    int wave = threadIdx.x >> 6;
    int bid = blockIdx.x;
    const unsigned* w2b = (const unsigned*)wc2;
    const unsigned* wsb = (const unsigned*)wcs;

    for (int i = 0; i < 4; i++) {
        int r = wave * 4 + i;
        int node = bid * 16 + r;
        float a2[KG], as[KG];
#pragma unroll
        for (int k = 0; k < KG; k++) { a2[k] = 0.0f; as[k] = 0.0f; }
        int beg = rfl(offs[node]);
        int end = rfl(offs[node + 1]);
        int cnt = end - beg;
        int sC = rfl(csr_src[clampe(beg + 2)]);
        int s0 = rfl(csr_src[clampe(beg + 0)]);
        int s1 = rfl(csr_src[clampe(beg + 1)]);
        float hv0 = ldx_frag(hf, s0, lane), xv0 = ldx_frag(Xf, s0, lane);
        float hv1 = ldx_frag(hf, s1, lane), xv1 = ldx_frag(Xf, s1, lane);
        const unsigned* p20 = w2b + (size_t)clampe(beg + 0) * 5;
        unsigned c0 = p20[0], c1 = p20[1], c2 = p20[2], c3 = p20[3], c4 = p20[4];
        const unsigned* ps0 = wsb + (size_t)clampe(beg + 0) * 5;
        unsigned d0 = ps0[0], d1 = ps0[1], d2 = ps0[2], d3 = ps0[3], d4 = ps0[4];
        const unsigned* p21 = w2b + (size_t)clampe(beg + 1) * 5;
        unsigned n0 = p21[0], n1 = p21[1], n2 = p21[2], n3 = p21[3], n4 = p21[4];
        const unsigned* ps1 = wsb + (size_t)clampe(beg + 1) * 5;
        unsigned o0 = ps1[0], o1 = ps1[1], o2 = ps1[2], o3 = ps1[3], o4 = ps1[4];
        for (int t = 0; t < cnt; ++t) {
            int sN = rfl(csr_src[clampe(beg + t + 3)]);
            float hv2 = ldx_frag(hf, sC, lane);
            float xv2 = ldx_frag(Xf, sC, lane);
            const unsigned* p22 = w2b + (size_t)clampe(beg + t + 2) * 5;
            unsigned m0 = p22[0], m1 = p22[1], m2 = p22[2], m3 = p22[3], m4 = p22[4];
            const unsigned* ps2 = wsb + (size_t)clampe(beg + t + 2) * 5;
            unsigned q0 = ps2[0], q1 = ps2[1], q2 = ps2[2], q3 = ps2[3], q4 = ps2[4];
            a2[0] += blo(c0) * hv0; a2[1] += bhi(c0) * hv0;
            a2[2] += blo(c1) * hv0; a2[3] += bhi(c1) * hv0;
            a2[4] += blo(c2) * hv0; a2[5] += bhi(c2) * hv0;
            a2[6] += blo(c3) * hv0; a2[7] += bhi(c3) * hv0;
            a2[8] += blo(c4) * hv0; a2[9] += bhi(c4) * hv0;
            as[0] += blo(d0) * xv0; as[1] += bhi(d0) * xv0;
            as[2] += blo(d1) * xv0; as[3] += bhi(d1) * xv0;
            as[4] += blo(d2) * xv0; as[5] += bhi(d2) * xv0;
            as[6] += blo(d3) * xv0; as[7] += bhi(d3) * xv0;
            as[8] += blo(d4) * xv0; as[9] += bhi(d4) * xv0;
            hv0 = hv1; hv1 = hv2; xv0 = xv1; xv1 = xv2; sC = sN;
            c0 = n0; c1 = n1; c2 = n2; c3 = n3; c4 = n4;
            n0 = m0; n1 = m1; n2 = m2; n3 = m3; n4 = m4;
            d0 = o0; d1 = o1; d2 = o2; d3 = o3; d4 = o4;
            o0 = q0; o1 = q1; o2 = q2; o3 = q3; o4 = q4;
        }
        float inv = invdeg[node];
        store_zlds(z2, r, lane, a2, inv);
        store_zlds(zs, r, lane, as, inv);
    }
    __syncthreads();

    // GEMM: 16 rows x 128 cols; wave handles col-tiles wave and wave+4;
    // acc accumulates conv2 (A=z2/hf-root, B=wt2p) + shortcut (A=zs/Xf-root, B=wtsp)
    int m = lane & 15, quad = lane >> 4;
    int row0 = bid * 16;
    const bf16* hrow = hf + ((size_t)(row0 + m)) * 32 + quad * 8;
    const bf16* xrow = Xf + ((size_t)(row0 + m)) * 32 + quad * 8;
    int f = flag[0];
#pragma unroll
    for (int tt = 0; tt < 2; tt++) {
        int n = wave + tt * 4;
        float4v acc4 = (float4v){0.f, 0.f, 0.f, 0.f};
        const bf16* b2row = wt2p + ((size_t)(n * 22) * 64 + lane) * 8;
        const bf16* bsrow = wtsp + ((size_t)(n * 22) * 64 + lane) * 8;
#pragma unroll
        for (int kc = 0; kc < 22; kc++) {
            short8 a = (kc < 20)
                ? *(const short8*)(z2 + kc * ZKS + m * ZRS + quad * 8)
                : *(const short8*)(hrow + (size_t)(kc - 20) * NP * 32);
            short8 b = *(const short8*)(b2row + (size_t)kc * 512);
            acc4 = __builtin_amdgcn_mfma_f32_16x16x32_bf16(a, b, acc4, 0, 0, 0);
        }
#pragma unroll
        for (int kc = 0; kc < 22; kc++) {
            short8 a = (kc < 20)
                ? *(const short8*)(zs + kc * ZKS + m * ZRS + quad * 8)
                : *(const short8*)(xrow + (size_t)(kc - 20) * NP * 32);
            short8 b = *(const short8*)(bsrow + (size_t)kc * 512);
            acc4 = __builtin_amdgcn_mfma_f32_16x16x32_bf16(a, b, acc4, 0, 0, 0);
        }
        int gcol = n * 16 + m;
        float bv = ldf(b2, gcol, f) + ldf(bs, gcol, f);
#pragma unroll
        for (int r = 0; r < 4; r++) {
            int grow = row0 + quad * 4 + r;
            if (grow >= N_NODES) continue;
            float v = fmaxf(acc4[r] + bv, 0.f);
            size_t oidx = (size_t)grow * 128 + gcol;
            if (f) ((float*)out)[oidx] = v;
            else   ((bf16*)out)[oidx] = __float2bfloat16(v);
        }
    }
}

extern "C" void kernel_launch(void* const* d_in, const int* in_sizes, int n_in,
                              void* d_out, int out_size, void* d_ws, size_t ws_size,
                              hipStream_t stream) {
    const void* x      = d_in[0];
    const int*  ei     = (const int*)d_in[1];
    const void* pseudo = d_in[2];
    const void* g1     = d_in[3];
    const void* mu1    = d_in[4];
    const void* sg1    = d_in[5];
    const void* root1  = d_in[6];
    const void* b1     = d_in[7];
    const void* g2     = d_in[8];
    const void* mu2    = d_in[9];
    const void* sg2    = d_in[10];
    const void* root2  = d_in[11];
    const void* b2     = d_in[12];
    const void* gs     = d_in[13];
    const void* mus    = d_in[14];
    const void* sgs    = d_in[15];
    const void* roots  = d_in[16];
    const void* bs     = d_in[17];

    char* ws = (char*)d_ws;
    size_t off = 0;
    auto alloc = [&](size_t bytes) -> char* {
        char* p = ws + off;
        off += (bytes + 255) & ~(size_t)255;
        return p;
    };
    const size_t XFS = (size_t)2 * NP * 32 * 2;      // 5.25 MB frag-layout x/h

    int*   flag   = (int*)alloc(256);
    int*   deg    = (int*)alloc((size_t)NP * 4);
    int*   offs   = (int*)alloc((size_t)(NP + 1) * 4);
    int*   cur    = (int*)alloc((size_t)NP * 4);
    float* invdeg = (float*)alloc((size_t)NP * 4);
    int*   bsum   = (int*)alloc((size_t)NBLK * 4);
    int*   ep     = (int*)alloc((size_t)N_EDGES * 4);
    int*   csrs   = (int*)alloc((size_t)N_EDGES * 4);
    bf16*  Xf     = (bf16*)alloc(XFS);
    bf16*  hf     = (bf16*)alloc(XFS);
    bf16*  wt1p   = (bf16*)alloc((size_t)64 * 704 * 2);
    bf16*  wt2p   = (bf16*)alloc((size_t)128 * 704 * 2);
    bf16*  wtsp   = (bf16*)alloc((size_t)128 * 704 * 2);
    bf16*  wc1    = (bf16*)alloc((size_t)N_EDGES * 10 * 2);   // w1 csr-order
    bf16*  wcs    = (bf16*)alloc((size_t)N_EDGES * 10 * 2);   // ws csr-order
    bf16*  wc2    = (bf16*)alloc((size_t)N_EDGES * 10 * 2);   // w2 csr-order
    (void)ws_size;

    hipMemsetAsync(deg, 0, (size_t)NP * 4, stream);
    k_detect_count<<<1 + (N_EDGES + 255) / 256, 256, 0, stream>>>(x, ei, flag, deg);
    k_scan1<<<NBLK, SCAN_B, 0, stream>>>(deg, offs, bsum);
    k_scan3m<<<NBLK, 256, 0, stream>>>(offs, bsum, deg, cur, invdeg);
    k_fill<<<(N_EDGES + 255) / 256, 256, 0, stream>>>(ei, cur, ep, csrs);
    k_prep_all<<<CVT_BLK + W3_BLK + PACK_BLK, 256, 0, stream>>>(
        x, pseudo, mu1, sg1, mu2, sg2, mus, sgs, g1, root1, g2, root2, gs, roots,
        flag, ep, Xf, wc1, wcs, wc2, wt1p, wt2p, wtsp);
    k_fused1<<<GRIDF, 256, 0, stream>>>(offs, csrs, wc1, invdeg, Xf, wt1p, b1,
                                        flag, hf);
    k_fused2<<<GRIDF, 256, 0, stream>>>(offs, csrs, wc2, wcs, invdeg, Xf, hf,
                                        wt2p, wtsp, b2, bs, flag, d_out);
}

// Round 4
// 273.275 us; speedup vs baseline: 1.0225x; 1.0225x over previous
//
#include <hip/hip_runtime.h>
#include <hip/hip_bf16.h>

using bf16 = __hip_bfloat16;
typedef __attribute__((ext_vector_type(8))) short short8;
typedef __attribute__((ext_vector_type(4))) float float4v;

#define N_NODES 40962
#define N_EDGES 245760
#define NP      41024      // 641*64, padded node count
#define KG      10
#define SCAN_B  256
#define NBLK    ((NP + SCAN_B - 1) / SCAN_B)   // 161
#define GRIDF   (NP / 16)                      // 2564 fused blocks (16 rows each)

// fused prep grid partition
#define CVT_V   (N_NODES * 64 / 8)             // 327696 vectors of 8
#define CVT_BLK ((CVT_V + 255) / 256)          // 1281
#define W3_BLK  (N_EDGES / 256)                // 960
#define PACK_N  (64 * 704 + 2 * 128 * 704)     // 225280
#define PACK_BLK (PACK_N / 256)                // 880

// k-dim ordering (shared by z LDS stores, x/h frag layout, and B pack):
//   k in [0,512):   cin = k>>3,        kg = k&7      (k = cin*8+kg)
//   k in [512,640): cin = (k-512)>>1,  kg = 8+((k-512)&1)
//   k in [640,704): root row cin = k-640
// Frag layouts (memory layout == MFMA fragment layout):
//   Xf/hf[c][node][32] c=0..1   : element t -> cin = c*32+t (root part)
//   Bp[((n*22+kc)*64+lane)*8+j] : col = n*16+(lane&15), k = kc*32+(lane>>4)*8+j
// CSR-ordered edge data: csr_src[pos]=source node; wc1/wcs/wc2[pos*5 u32] =
// packed bf16 weight pairs (sequential per node in the gathers).
//
// LDS z tile: z[chunk][16 rows], row stride ZRS=40 elems (80 B), chunk stride
// ZKS=672 elems (1344 B = 84 x 16B slots, 84 % 8 == 4).  Bank math (16B slots
// mod 8): b128 write slot = 4*chunk + sub -> exact 2-way (free, m136);
// b128 read slot = 5*m -> 2-way; 4B tail covers all 32 banks exactly 2x.
#define ZRS  40
#define ZKS  672
#define ZSZE 13440   // 20 chunks * 672 elems = 26880 B

// flag[0] == 1 -> float inputs/outputs are f32 ; 0 -> bf16
__device__ __forceinline__ float ldf(const void* p, size_t i, int isf32) {
    return isf32 ? ((const float*)p)[i] : __bfloat162float(((const bf16*)p)[i]);
}
__device__ __forceinline__ float blo(unsigned u) { return __uint_as_float(u << 16); }
__device__ __forceinline__ float bhi(unsigned u) { return __uint_as_float(u & 0xffff0000u); }
__device__ __forceinline__ unsigned pk2(float a, float b) {
    union { bf16 h[2]; unsigned u; } t;
    t.h[0] = __float2bfloat16(a);
    t.h[1] = __float2bfloat16(b);
    return t.u;
}
__device__ __forceinline__ int rfl(int v) { return __builtin_amdgcn_readfirstlane(v); }

// ---------------- fused dtype detector + degree count ----------------
__global__ void k_detect_count(const void* x, const int* __restrict__ ei,
                               int* __restrict__ flag, int* __restrict__ deg) {
    if (blockIdx.x == 0) {
        __shared__ int huge_c, zero_even;
        if (threadIdx.x == 0) { huge_c = 0; zero_even = 0; }
        __syncthreads();
        const bf16* xb = (const bf16*)x;
        int lh = 0, lz = 0;
        for (int i = threadIdx.x; i < 8192; i += 256) {
            float v = __bfloat162float(xb[i]);
            if (!(fabsf(v) <= 1e4f)) lh++;
            if ((i & 1) == 0 && v == 0.0f) lz++;
        }
        atomicAdd(&huge_c, lh);
        atomicAdd(&zero_even, lz);
        __syncthreads();
        if (threadIdx.x == 0) flag[0] = (huge_c > 0 || zero_even > 3000) ? 1 : 0;
    } else {
        int e = (blockIdx.x - 1) * 256 + threadIdx.x;
        if (e < N_EDGES) atomicAdd(&deg[ei[N_EDGES + e]], 1);
    }
}

// ---------------- scan stage 1: block-local exclusive + block sums ----------------
__global__ void k_scan1(const int* __restrict__ deg, int* __restrict__ offs,
                        int* __restrict__ bsum) {
    __shared__ int buf[SCAN_B];
    int t = threadIdx.x, b = blockIdx.x;
    int i = b * SCAN_B + t;
    int v = (i < NP) ? deg[i] : 0;
    buf[t] = v;
    __syncthreads();
    for (int off = 1; off < SCAN_B; off <<= 1) {
        int a = (t >= off) ? buf[t - off] : 0;
        __syncthreads();
        buf[t] += a;
        __syncthreads();
    }
    if (i < NP) offs[i] = buf[t] - v;
    if (t == SCAN_B - 1) bsum[b] = buf[t];
}

// ---------------- scan stage 2 (merged): each block re-scans bsum locally ----------------
__global__ void k_scan3m(int* __restrict__ offs, const int* __restrict__ bsum,
                         const int* __restrict__ deg, int* __restrict__ cur,
                         float* __restrict__ invdeg) {
    __shared__ int buf[256];
    int t = threadIdx.x, b = blockIdx.x;
    int v = (t < NBLK) ? bsum[t] : 0;
    buf[t] = v;
    __syncthreads();
    for (int off = 1; off < 256; off <<= 1) {
        int a = (t >= off) ? buf[t - off] : 0;
        __syncthreads();
        buf[t] += a;
        __syncthreads();
    }
    int bofs = (b > 0) ? buf[b - 1] : 0;
    int total = buf[NBLK - 1];
    int i = b * 256 + t;
    if (i < NP) {
        int o = offs[i] + bofs;
        offs[i] = o;
        cur[i] = o;
        int d = deg[i];
        invdeg[i] = 1.0f / (float)(d > 1 ? d : 1);
    }
    if (i == 0) offs[NP] = total;
}

// ---------------- CSR fill: pos per edge, src in CSR order ----------------
__global__ void k_fill(const int* __restrict__ ei, int* __restrict__ cur,
                       int* __restrict__ ep, int* __restrict__ csr_src) {
    int e = blockIdx.x * 256 + threadIdx.x;
    if (e < N_EDGES) {
        int pos = atomicAdd(&cur[ei[N_EDGES + e]], 1);
        ep[e] = pos;
        csr_src[pos] = ei[e];
    }
}

// ---------------- gaussian weights helper ----------------
__device__ __forceinline__ void gw_one(float p0, float p1, const void* mu,
                                       const void* sg, int f, float* out) {
#pragma unroll
    for (int k = 0; k < KG; k++) {
        float m0 = ldf(mu, 2 * k + 0, f), m1 = ldf(mu, 2 * k + 1, f);
        float s0 = ldf(sg, 2 * k + 0, f), s1 = ldf(sg, 2 * k + 1, f);
        float d0 = p0 - m0, d1 = p1 - m1;
        float t = -0.5f * (d0 * d0 / (1e-15f + s0 * s0) + d1 * d1 / (1e-15f + s1 * s1));
        out[k] = __expf(t);
    }
}

// ---------------- B pack in fragment order ----------------
__device__ __forceinline__ void pack_frag(const void* g, const void* root, int f,
                                          int idx, int Cout, bf16* Bp) {
    int j = idx & 7;
    int lane = (idx >> 3) & 63;
    int rem = idx >> 9;
    int kc = rem % 22;
    int n = rem / 22;
    int col = n * 16 + (lane & 15);
    int k = kc * 32 + (lane >> 4) * 8 + j;
    float v;
    if (k < 512) {
        int cin = k >> 3, kg = k & 7;
        v = ldf(g, (size_t)cin * (KG * Cout) + (size_t)kg * Cout + col, f);
    } else if (k < 640) {
        int jj = k - 512;
        int cin = jj >> 1, kg = 8 + (jj & 1);
        v = ldf(g, (size_t)cin * (KG * Cout) + (size_t)kg * Cout + col, f);
    } else {
        v = ldf(root, (size_t)(k - 640) * Cout + col, f);
    }
    Bp[idx] = __float2bfloat16(v);
}

// ---------------- fused prep: cvt x->Xf | w3 (CSR-order writes) | pack3 ---------
// NOTE: must run AFTER k_fill (reads ep[] for csr-order weight placement).
__global__ void k_prep_all(const void* __restrict__ x, const void* __restrict__ pseudo,
                           const void* mu1, const void* sg1, const void* mu2,
                           const void* sg2, const void* mus, const void* sgs,
                           const void* g1, const void* root1, const void* g2,
                           const void* root2, const void* gs, const void* roots,
                           const int* __restrict__ flag, const int* __restrict__ ep,
                           bf16* __restrict__ Xf, bf16* __restrict__ wc1,
                           bf16* __restrict__ wcs, bf16* __restrict__ wc2,
                           bf16* wt1p, bf16* wt2p, bf16* wtsp) {
    int b = blockIdx.x;
    int tid = threadIdx.x;
    int f = flag[0];
    if (b < CVT_BLK) {
        int i = b * 256 + tid;
        if (i < CVT_V) {
            int node = i >> 3, j = i & 7;   // covers x[node][j*8 .. j*8+8)
            uint4 u;
            if (f) {
                const float4* xf = (const float4*)x;
                float4 a = xf[2 * i], c = xf[2 * i + 1];
                union { bf16 t[8]; uint4 u; } tt;
                tt.t[0] = __float2bfloat16(a.x); tt.t[1] = __float2bfloat16(a.y);
                tt.t[2] = __float2bfloat16(a.z); tt.t[3] = __float2bfloat16(a.w);
                tt.t[4] = __float2bfloat16(c.x); tt.t[5] = __float2bfloat16(c.y);
                tt.t[6] = __float2bfloat16(c.z); tt.t[7] = __float2bfloat16(c.w);
                u = tt.u;
            } else {
                u = ((const uint4*)x)[i];
            }
            *(uint4*)(Xf + ((size_t)(j >> 2) * NP + node) * 32 + (j & 3) * 8) = u;
        }
    } else if (b < CVT_BLK + W3_BLK) {
        int e = (b - CVT_BLK) * 256 + tid;
        float p0 = ldf(pseudo, (size_t)e * 2 + 0, f);
        float p1 = ldf(pseudo, (size_t)e * 2 + 1, f);
        float o1[KG], o2[KG], os[KG];
        gw_one(p0, p1, mu1, sg1, f, o1);
        gw_one(p0, p1, mu2, sg2, f, o2);
        gw_one(p0, p1, mus, sgs, f, os);
        int pos = ep[e];
        unsigned* d1 = (unsigned*)wc1 + (size_t)pos * 5;
        d1[0] = pk2(o1[0], o1[1]); d1[1] = pk2(o1[2], o1[3]);
        d1[2] = pk2(o1[4], o1[5]); d1[3] = pk2(o1[6], o1[7]);
        d1[4] = pk2(o1[8], o1[9]);
        unsigned* ds = (unsigned*)wcs + (size_t)pos * 5;
        ds[0] = pk2(os[0], os[1]); ds[1] = pk2(os[2], os[3]);
        ds[2] = pk2(os[4], os[5]); ds[3] = pk2(os[6], os[7]);
        ds[4] = pk2(os[8], os[9]);
        unsigned* d2 = (unsigned*)wc2 + (size_t)pos * 5;
        d2[0] = pk2(o2[0], o2[1]); d2[1] = pk2(o2[2], o2[3]);
        d2[2] = pk2(o2[4], o2[5]); d2[3] = pk2(o2[6], o2[7]);
        d2[4] = pk2(o2[8], o2[9]);
    } else {
        int idx = (b - CVT_BLK - W3_BLK) * 256 + tid;
        if (idx < 64 * 704) {
            pack_frag(g1, root1, f, idx, 64, wt1p);
        } else if (idx < 64 * 704 + 128 * 704) {
            pack_frag(g2, root2, f, idx - 64 * 704, 128, wt2p);
        } else {
            pack_frag(gs, roots, f, idx - 64 * 704 - 128 * 704, 128, wtsp);
        }
    }
}

// X frag-layout read: cin = lane -> chunk lane>>5, t = lane&31
__device__ __forceinline__ float ldx_frag(const bf16* X, int src, int lane) {
    return __bfloat162float(X[((size_t)(lane >> 5) * NP + src) * 32 + (lane & 31)]);
}

__device__ __forceinline__ int clampe(int idx) {
    return idx > N_EDGES - 1 ? N_EDGES - 1 : idx;
}

// ---------------- one node's gather: scalarized weights + 2-deep X prefetch -----
__device__ __forceinline__ void gather_one(const int* __restrict__ offs,
                                           const int* __restrict__ csr_src,
                                           const unsigned* __restrict__ wb,
                                           const bf16* __restrict__ X, int node,
                                           int lane, float* acc) {
#pragma unroll
    for (int k = 0; k < KG; k++) acc[k] = 0.0f;
    int beg = rfl(offs[node]);
    int end = rfl(offs[node + 1]);
    int cnt = end - beg;
    int sC = rfl(csr_src[clampe(beg + 2)]);
    float xv0 = ldx_frag(X, rfl(csr_src[clampe(beg + 0)]), lane);
    float xv1 = ldx_frag(X, rfl(csr_src[clampe(beg + 1)]), lane);
    const unsigned* wp0 = wb + (size_t)clampe(beg + 0) * 5;
    unsigned c0 = wp0[0], c1 = wp0[1], c2 = wp0[2], c3 = wp0[3], c4 = wp0[4];
    const unsigned* wp1 = wb + (size_t)clampe(beg + 1) * 5;
    unsigned n0 = wp1[0], n1 = wp1[1], n2 = wp1[2], n3 = wp1[3], n4 = wp1[4];
    for (int t = 0; t < cnt; ++t) {
        int sN = rfl(csr_src[clampe(beg + t + 3)]);
        float xv2 = ldx_frag(X, sC, lane);
        const unsigned* wp2 = wb + (size_t)clampe(beg + t + 2) * 5;
        unsigned m0 = wp2[0], m1 = wp2[1], m2 = wp2[2], m3 = wp2[3], m4 = wp2[4];
        acc[0] += blo(c0) * xv0; acc[1] += bhi(c0) * xv0;
        acc[2] += blo(c1) * xv0; acc[3] += bhi(c1) * xv0;
        acc[4] += blo(c2) * xv0; acc[5] += bhi(c2) * xv0;
        acc[6] += blo(c3) * xv0; acc[7] += bhi(c3) * xv0;
        acc[8] += blo(c4) * xv0; acc[9] += bhi(c4) * xv0;
        xv0 = xv1; xv1 = xv2; sC = sN;
        c0 = n0; c1 = n1; c2 = n2; c3 = n3; c4 = n4;
        n0 = m0; n1 = m1; n2 = m2; n3 = m3; n4 = m4;
    }
}

// ---------------- z store into LDS tile (conflict-free strides) ----------------
__device__ __forceinline__ void store_zlds(bf16* z, int r, int lane, const float* a,
                                           float inv) {
    union { bf16 h[8]; uint4 u; } p;
#pragma unroll
    for (int k = 0; k < 8; k++) p.h[k] = __float2bfloat16(a[k] * inv);
    *(uint4*)(z + (lane >> 2) * ZKS + r * ZRS + (lane & 3) * 8) = p.u;
    *(unsigned*)(z + (16 + (lane >> 4)) * ZKS + r * ZRS + (lane & 15) * 2) =
        pk2(a[8] * inv, a[9] * inv);
}

// ---------------- fused conv1: 8-wave gather(x,w1)->LDS + 4-wave GEMM -> hf -----
__global__ __launch_bounds__(512) void k_fused1(
    const int* __restrict__ offs, const int* __restrict__ csr_src,
    const bf16* __restrict__ wc1, const float* __restrict__ invdeg,
    const bf16* __restrict__ Xf, const bf16* __restrict__ wt1p,
    const void* __restrict__ b1, const int* __restrict__ flag,
    bf16* __restrict__ hf) {
    __shared__ bf16 zA[ZSZE];
    int lane = threadIdx.x & 63;
    int wave = threadIdx.x >> 6;
    int bid = blockIdx.x;
    const unsigned* wb = (const unsigned*)wc1;

#pragma unroll
    for (int i = 0; i < 2; i++) {
        int r = wave * 2 + i;
        int node = bid * 16 + r;
        float acc[KG];
        gather_one(offs, csr_src, wb, Xf, node, lane, acc);
        store_zlds(zA, r, lane, acc, invdeg[node]);
    }
    __syncthreads();

    if (wave < 4) {
        // GEMM: 16 rows x 64 cols; col-tile n = wave; A from LDS + Xf root rows
        int m = lane & 15, quad = lane >> 4;
        int row0 = bid * 16;
        float4v acc4 = (float4v){0.f, 0.f, 0.f, 0.f};
        const bf16* brow = wt1p + ((size_t)(wave * 22) * 64 + lane) * 8;
        const bf16* xrow = Xf + ((size_t)(row0 + m)) * 32 + quad * 8;
#pragma unroll
        for (int kc = 0; kc < 22; kc++) {
            short8 a = (kc < 20)
                ? *(const short8*)(zA + kc * ZKS + m * ZRS + quad * 8)
                : *(const short8*)(xrow + (size_t)(kc - 20) * NP * 32);
            short8 b = *(const short8*)(brow + (size_t)kc * 512);
            acc4 = __builtin_amdgcn_mfma_f32_16x16x32_bf16(a, b, acc4, 0, 0, 0);
        }
        int f = flag[0];
        int gcol = wave * 16 + m;
        float bv = ldf(b1, gcol, f);
#pragma unroll
        for (int r = 0; r < 4; r++) {
            int grow = row0 + quad * 4 + r;
            if (grow >= N_NODES) continue;
            float v = fmaxf(acc4[r] + bv, 0.f);
            hf[((size_t)(gcol >> 5) * NP + grow) * 32 + (gcol & 31)] =
                __float2bfloat16(v);
        }
    }
}

// ---------------- fused conv2+shortcut: two gather passes share one z tile ------
__global__ __launch_bounds__(512) void k_fused2(
    const int* __restrict__ offs, const int* __restrict__ csr_src,
    const bf16* __restrict__ wc2, const bf16* __restrict__ wcs,
    const float* __restrict__ invdeg, const bf16* __restrict__ Xf,
    const bf16* __restrict__ hf, const bf16* __restrict__ wt2p,
    const bf16* __restrict__ wtsp, const void* __restrict__ b2,
    const void* __restrict__ bs, const int* __restrict__ flag,
    void* __restrict__ out) {
    __shared__ bf16 z[ZSZE];
    int lane = threadIdx.x & 63;
    int wave = threadIdx.x >> 6;
    int bid = blockIdx.x;
    int m = lane & 15, quad = lane >> 4;
    int row0 = bid * 16;

    // pass A: conv2 gather (hf, wc2) -> z
#pragma unroll
    for (int i = 0; i < 2; i++) {
        int r = wave * 2 + i;
        int node = bid * 16 + r;
        float acc[KG];
        gather_one(offs, csr_src, (const unsigned*)wc2, hf, node, lane, acc);
        store_zlds(z, r, lane, acc, invdeg[node]);
    }
    __syncthreads();

    // conv2 GEMM: 16 rows x 128 cols, n = wave
    float4v acc4 = (float4v){0.f, 0.f, 0.f, 0.f};
    {
        const bf16* brow = wt2p + ((size_t)(wave * 22) * 64 + lane) * 8;
        const bf16* hrow = hf + ((size_t)(row0 + m)) * 32 + quad * 8;
#pragma unroll
        for (int kc = 0; kc < 22; kc++) {
            short8 a = (kc < 20)
                ? *(const short8*)(z + kc * ZKS + m * ZRS + quad * 8)
                : *(const short8*)(hrow + (size_t)(kc - 20) * NP * 32);
            short8 b = *(const short8*)(brow + (size_t)kc * 512);
            acc4 = __builtin_amdgcn_mfma_f32_16x16x32_bf16(a, b, acc4, 0, 0, 0);
        }
    }
    __syncthreads();   // all waves done reading z

    // pass B: shortcut gather (Xf, wcs) -> z (reuse tile)
#pragma unroll
    for (int i = 0; i < 2; i++) {
        int r = wave * 2 + i;
        int node = bid * 16 + r;
        float acc[KG];
        gather_one(offs, csr_src, (const unsigned*)wcs, Xf, node, lane, acc);
        store_zlds(z, r, lane, acc, invdeg[node]);
    }
    __syncthreads();

    // shortcut GEMM accumulates into the same acc4
    {
        const bf16* brow = wtsp + ((size_t)(wave * 22) * 64 + lane) * 8;
        const bf16* xrow = Xf + ((size_t)(row0 + m)) * 32 + quad * 8;
#pragma unroll
        for (int kc = 0; kc < 22; kc++) {
            short8 a = (kc < 20)
                ? *(const short8*)(z + kc * ZKS + m * ZRS + quad * 8)
                : *(const short8*)(xrow + (size_t)(kc - 20) * NP * 32);
            short8 b = *(const short8*)(brow + (size_t)kc * 512);
            acc4 = __builtin_amdgcn_mfma_f32_16x16x32_bf16(a, b, acc4, 0, 0, 0);
        }
    }

    int f = flag[0];
    int gcol = wave * 16 + m;
    float bv = ldf(b2, gcol, f) + ldf(bs, gcol, f);
#pragma unroll
    for (int r = 0; r < 4; r++) {
        int grow = row0 + quad * 4 + r;
        if (grow >= N_NODES) continue;
        float v = fmaxf(acc4[r] + bv, 0.f);
        size_t oidx = (size_t)grow * 128 + gcol;
        if (f) ((float*)out)[oidx] = v;
        else   ((bf16*)out)[oidx] = __float2bfloat16(v);
    }
}

extern "C" void kernel_launch(void* const* d_in, const int* in_sizes, int n_in,
                              void* d_out, int out_size, void* d_ws, size_t ws_size,
                              hipStream_t stream) {
    const void* x      = d_in[0];
    const int*  ei     = (const int*)d_in[1];
    const void* pseudo = d_in[2];
    const void* g1     = d_in[3];
    const void* mu1    = d_in[4];
    const void* sg1    = d_in[5];
    const void* root1  = d_in[6];
    const void* b1     = d_in[7];
    const void* g2     = d_in[8];
    const void* mu2    = d_in[9];
    const void* sg2    = d_in[10];
    const void* root2  = d_in[11];
    const void* b2     = d_in[12];
    const void* gs     = d_in[13];
    const void* mus    = d_in[14];
    const void* sgs    = d_in[15];
    const void* roots  = d_in[16];
    const void* bs     = d_in[17];

    char* ws = (char*)d_ws;
    size_t off = 0;
    auto alloc = [&](size_t bytes) -> char* {
        char* p = ws + off;
        off += (bytes + 255) & ~(size_t)255;
        return p;
    };
    const size_t XFS = (size_t)2 * NP * 32 * 2;      // 5.25 MB frag-layout x/h

    int*   flag   = (int*)alloc(256);
    int*   deg    = (int*)alloc((size_t)NP * 4);
    int*   offs   = (int*)alloc((size_t)(NP + 1) * 4);
    int*   cur    = (int*)alloc((size_t)NP * 4);
    float* invdeg = (float*)alloc((size_t)NP * 4);
    int*   bsum   = (int*)alloc((size_t)NBLK * 4);
    int*   ep     = (int*)alloc((size_t)N_EDGES * 4);
    int*   csrs   = (int*)alloc((size_t)N_EDGES * 4);
    bf16*  Xf     = (bf16*)alloc(XFS);
    bf16*  hf     = (bf16*)alloc(XFS);
    bf16*  wt1p   = (bf16*)alloc((size_t)64 * 704 * 2);
    bf16*  wt2p   = (bf16*)alloc((size_t)128 * 704 * 2);
    bf16*  wtsp   = (bf16*)alloc((size_t)128 * 704 * 2);
    bf16*  wc1    = (bf16*)alloc((size_t)N_EDGES * 10 * 2);   // w1 csr-order
    bf16*  wcs    = (bf16*)alloc((size_t)N_EDGES * 10 * 2);   // ws csr-order
    bf16*  wc2    = (bf16*)alloc((size_t)N_EDGES * 10 * 2);   // w2 csr-order
    (void)ws_size;

    hipMemsetAsync(deg, 0, (size_t)NP * 4, stream);
    k_detect_count<<<1 + (N_EDGES + 255) / 256, 256, 0, stream>>>(x, ei, flag, deg);
    k_scan1<<<NBLK, SCAN_B, 0, stream>>>(deg, offs, bsum);
    k_scan3m<<<NBLK, 256, 0, stream>>>(offs, bsum, deg, cur, invdeg);
    k_fill<<<(N_EDGES + 255) / 256, 256, 0, stream>>>(ei, cur, ep, csrs);
    k_prep_all<<<CVT_BLK + W3_BLK + PACK_BLK, 256, 0, stream>>>(
        x, pseudo, mu1, sg1, mu2, sg2, mus, sgs, g1, root1, g2, root2, gs, roots,
        flag, ep, Xf, wc1, wcs, wc2, wt1p, wt2p, wtsp);
    k_fused1<<<GRIDF, 512, 0, stream>>>(offs, csrs, wc1, invdeg, Xf, wt1p, b1,
                                        flag, hf);
    k_fused2<<<GRIDF, 512, 0, stream>>>(offs, csrs, wc2, wcs, invdeg, Xf, hf,
                                        wt2p, wtsp, b2, bs, flag, d_out);
}

// Round 6
// 270.856 us; speedup vs baseline: 1.0316x; 1.0089x over previous
//
#include <hip/hip_runtime.h>
#include <hip/hip_bf16.h>

using bf16 = __hip_bfloat16;
typedef __attribute__((ext_vector_type(8))) short short8;
typedef __attribute__((ext_vector_type(4))) float float4v;

#define N_NODES 40962
#define N_EDGES 245760
#define NP      41024      // 641*64, padded node count
#define KG      10
#define SCAN_B  256
#define NBLK    ((NP + SCAN_B - 1) / SCAN_B)   // 161
#define GRIDF   (NP / 16)                      // 2564 fused blocks (16 rows each)

// fused prep grid partition
#define CVT_V   (N_NODES * 64 / 8)             // 327696 vectors of 8
#define CVT_BLK ((CVT_V + 255) / 256)          // 1281
#define W3_BLK  (N_EDGES / 256)                // 960
#define PACK_N  (64 * 704 + 2 * 128 * 704)     // 225280
#define PACK_BLK (PACK_N / 256)                // 880

// k-dim ordering (shared by z LDS stores, x/h layout, and B pack):
//   k in [0,512):   cin = k>>3,        kg = k&7      (k = cin*8+kg)
//   k in [512,640): cin = (k-512)>>1,  kg = 8+((k-512)&1)
//   k in [640,704): root row cin = k-640
// Gather-lane mapping: lane holds cin=lane; acc[kg] -> k = lane*8+kg (kg<8),
// tail k = 512 + lane*2 + (kg-8).
// Xf/hf layout: [node][64] node-contiguous (one 128B burst per random read).
// Bp[((n*22+kc)*64+lane)*8+j] : col = n*16+(lane&15), k = kc*32+(lane>>4)*8+j
// CSR edge data: csr_src[pos]=src; wcab[pos*10 u32]={w1:5,ws:5}; wc2[pos*5].
//
// LDS z tile: z[r][k], row stride ZRS=680 elems (1360 B = 85 x 16B slots).
// Write: lane stores 16B at r*1360 + lane*16 -> linear, conflict-free.
// Read (GEMM): quarter-wave lanes m=0..15 at stride 85 slots; 85%8=5 coprime
// -> 16 lanes spread 2 per slot-class = 2-way (free, m136).
#define ZRS  680
#define ZT   10880   // 16*680 elems = 21760 B

// flag[0] == 1 -> float inputs/outputs are f32 ; 0 -> bf16
__device__ __forceinline__ float ldf(const void* p, size_t i, int isf32) {
    return isf32 ? ((const float*)p)[i] : __bfloat162float(((const bf16*)p)[i]);
}
__device__ __forceinline__ float blo(unsigned u) { return __uint_as_float(u << 16); }
__device__ __forceinline__ float bhi(unsigned u) { return __uint_as_float(u & 0xffff0000u); }
__device__ __forceinline__ unsigned pk2(float a, float b) {
    union { bf16 h[2]; unsigned u; } t;
    t.h[0] = __float2bfloat16(a);
    t.h[1] = __float2bfloat16(b);
    return t.u;
}
__device__ __forceinline__ int rfl(int v) { return __builtin_amdgcn_readfirstlane(v); }

// ---------------- fused dtype detector + degree count ----------------
__global__ void k_detect_count(const void* x, const int* __restrict__ ei,
                               int* __restrict__ flag, int* __restrict__ deg) {
    if (blockIdx.x == 0) {
        __shared__ int huge_c, zero_even;
        if (threadIdx.x == 0) { huge_c = 0; zero_even = 0; }
        __syncthreads();
        const bf16* xb = (const bf16*)x;
        int lh = 0, lz = 0;
        for (int i = threadIdx.x; i < 8192; i += 256) {
            float v = __bfloat162float(xb[i]);
            if (!(fabsf(v) <= 1e4f)) lh++;
            if ((i & 1) == 0 && v == 0.0f) lz++;
        }
        atomicAdd(&huge_c, lh);
        atomicAdd(&zero_even, lz);
        __syncthreads();
        if (threadIdx.x == 0) flag[0] = (huge_c > 0 || zero_even > 3000) ? 1 : 0;
    } else {
        int e = (blockIdx.x - 1) * 256 + threadIdx.x;
        if (e < N_EDGES) atomicAdd(&deg[ei[N_EDGES + e]], 1);
    }
}

// ---------------- scan stage 1: block-local exclusive + block sums ----------------
__global__ void k_scan1(const int* __restrict__ deg, int* __restrict__ offs,
                        int* __restrict__ bsum) {
    __shared__ int buf[SCAN_B];
    int t = threadIdx.x, b = blockIdx.x;
    int i = b * SCAN_B + t;
    int v = (i < NP) ? deg[i] : 0;
    buf[t] = v;
    __syncthreads();
    for (int off = 1; off < SCAN_B; off <<= 1) {
        int a = (t >= off) ? buf[t - off] : 0;
        __syncthreads();
        buf[t] += a;
        __syncthreads();
    }
    if (i < NP) offs[i] = buf[t] - v;
    if (t == SCAN_B - 1) bsum[b] = buf[t];
}

// ---------------- scan stage 2 (merged): each block re-scans bsum locally ----------------
__global__ void k_scan3m(int* __restrict__ offs, const int* __restrict__ bsum,
                         const int* __restrict__ deg, int* __restrict__ cur,
                         float* __restrict__ invdeg) {
    __shared__ int buf[256];
    int t = threadIdx.x, b = blockIdx.x;
    int v = (t < NBLK) ? bsum[t] : 0;
    buf[t] = v;
    __syncthreads();
    for (int off = 1; off < 256; off <<= 1) {
        int a = (t >= off) ? buf[t - off] : 0;
        __syncthreads();
        buf[t] += a;
        __syncthreads();
    }
    int bofs = (b > 0) ? buf[b - 1] : 0;
    int total = buf[NBLK - 1];
    int i = b * 256 + t;
    if (i < NP) {
        int o = offs[i] + bofs;
        offs[i] = o;
        cur[i] = o;
        int d = deg[i];
        invdeg[i] = 1.0f / (float)(d > 1 ? d : 1);
    }
    if (i == 0) offs[NP] = total;
}

// ---------------- CSR fill: pos per edge, src in CSR order ----------------
__global__ void k_fill(const int* __restrict__ ei, int* __restrict__ cur,
                       int* __restrict__ ep, int* __restrict__ csr_src) {
    int e = blockIdx.x * 256 + threadIdx.x;
    if (e < N_EDGES) {
        int pos = atomicAdd(&cur[ei[N_EDGES + e]], 1);
        ep[e] = pos;
        csr_src[pos] = ei[e];
    }
}

// ---------------- gaussian weights helper ----------------
__device__ __forceinline__ void gw_one(float p0, float p1, const void* mu,
                                       const void* sg, int f, float* out) {
#pragma unroll
    for (int k = 0; k < KG; k++) {
        float m0 = ldf(mu, 2 * k + 0, f), m1 = ldf(mu, 2 * k + 1, f);
        float s0 = ldf(sg, 2 * k + 0, f), s1 = ldf(sg, 2 * k + 1, f);
        float d0 = p0 - m0, d1 = p1 - m1;
        float t = -0.5f * (d0 * d0 / (1e-15f + s0 * s0) + d1 * d1 / (1e-15f + s1 * s1));
        out[k] = __expf(t);
    }
}

// ---------------- B pack in fragment order ----------------
__device__ __forceinline__ void pack_frag(const void* g, const void* root, int f,
                                          int idx, int Cout, bf16* Bp) {
    int j = idx & 7;
    int lane = (idx >> 3) & 63;
    int rem = idx >> 9;
    int kc = rem % 22;
    int n = rem / 22;
    int col = n * 16 + (lane & 15);
    int k = kc * 32 + (lane >> 4) * 8 + j;
    float v;
    if (k < 512) {
        int cin = k >> 3, kg = k & 7;
        v = ldf(g, (size_t)cin * (KG * Cout) + (size_t)kg * Cout + col, f);
    } else if (k < 640) {
        int jj = k - 512;
        int cin = jj >> 1, kg = 8 + (jj & 1);
        v = ldf(g, (size_t)cin * (KG * Cout) + (size_t)kg * Cout + col, f);
    } else {
        v = ldf(root, (size_t)(k - 640) * Cout + col, f);
    }
    Bp[idx] = __float2bfloat16(v);
}

// ---------------- fused prep: cvt x->Xf | w3 (CSR-order writes) | pack3 ---------
// NOTE: must run AFTER k_fill (reads ep[] for csr-order weight placement).
__global__ void k_prep_all(const void* __restrict__ x, const void* __restrict__ pseudo,
                           const void* mu1, const void* sg1, const void* mu2,
                           const void* sg2, const void* mus, const void* sgs,
                           const void* g1, const void* root1, const void* g2,
                           const void* root2, const void* gs, const void* roots,
                           const int* __restrict__ flag, const int* __restrict__ ep,
                           bf16* __restrict__ Xf, bf16* __restrict__ wcab,
                           bf16* __restrict__ wc2, bf16* wt1p, bf16* wt2p,
                           bf16* wtsp) {
    int b = blockIdx.x;
    int tid = threadIdx.x;
    int f = flag[0];
    if (b < CVT_BLK) {
        int i = b * 256 + tid;
        if (i < CVT_V) {
            int node = i >> 3, j = i & 7;   // covers x[node][j*8 .. j*8+8)
            uint4 u;
            if (f) {
                const float4* xf = (const float4*)x;
                float4 a = xf[2 * i], c = xf[2 * i + 1];
                union { bf16 t[8]; uint4 u; } tt;
                tt.t[0] = __float2bfloat16(a.x); tt.t[1] = __float2bfloat16(a.y);
                tt.t[2] = __float2bfloat16(a.z); tt.t[3] = __float2bfloat16(a.w);
                tt.t[4] = __float2bfloat16(c.x); tt.t[5] = __float2bfloat16(c.y);
                tt.t[6] = __float2bfloat16(c.z); tt.t[7] = __float2bfloat16(c.w);
                u = tt.u;
            } else {
                u = ((const uint4*)x)[i];
            }
            *(uint4*)(Xf + (size_t)node * 64 + j * 8) = u;
        }
    } else if (b < CVT_BLK + W3_BLK) {
        int e = (b - CVT_BLK) * 256 + tid;
        float p0 = ldf(pseudo, (size_t)e * 2 + 0, f);
        float p1 = ldf(pseudo, (size_t)e * 2 + 1, f);
        float o1[KG], o2[KG], os[KG];
        gw_one(p0, p1, mu1, sg1, f, o1);
        gw_one(p0, p1, mu2, sg2, f, o2);
        gw_one(p0, p1, mus, sgs, f, os);
        int pos = ep[e];
        unsigned* d = (unsigned*)wcab + (size_t)pos * 10;
        d[0] = pk2(o1[0], o1[1]); d[1] = pk2(o1[2], o1[3]);
        d[2] = pk2(o1[4], o1[5]); d[3] = pk2(o1[6], o1[7]);
        d[4] = pk2(o1[8], o1[9]);
        d[5] = pk2(os[0], os[1]); d[6] = pk2(os[2], os[3]);
        d[7] = pk2(os[4], os[5]); d[8] = pk2(os[6], os[7]);
        d[9] = pk2(os[8], os[9]);
        unsigned* d2 = (unsigned*)wc2 + (size_t)pos * 5;
        d2[0] = pk2(o2[0], o2[1]); d2[1] = pk2(o2[2], o2[3]);
        d2[2] = pk2(o2[4], o2[5]); d2[3] = pk2(o2[6], o2[7]);
        d2[4] = pk2(o2[8], o2[9]);
    } else {
        int idx = (b - CVT_BLK - W3_BLK) * 256 + tid;
        if (idx < 64 * 704) {
            pack_frag(g1, root1, f, idx, 64, wt1p);
        } else if (idx < 64 * 704 + 128 * 704) {
            pack_frag(g2, root2, f, idx - 64 * 704, 128, wt2p);
        } else {
            pack_frag(gs, roots, f, idx - 64 * 704 - 128 * 704, 128, wtsp);
        }
    }
}

// node-contiguous X read: lane holds cin=lane
__device__ __forceinline__ float ldxf(const bf16* X, int src, int lane) {
    return __bfloat162float(X[(size_t)src * 64 + lane]);
}

__device__ __forceinline__ int clampe(int idx) {
    return idx > N_EDGES - 1 ? N_EDGES - 1 : idx;
}

// ---------------- z store into LDS tile [r][k] (linear, conflict-free) ---------
__device__ __forceinline__ void store_zlds(bf16* z, int r, int lane, const float* a,
                                           float inv) {
    union { bf16 h[8]; uint4 u; } p;
#pragma unroll
    for (int k = 0; k < 8; k++) p.h[k] = __float2bfloat16(a[k] * inv);
    *(uint4*)(z + r * ZRS + lane * 8) = p.u;
    *(unsigned*)(z + r * ZRS + 512 + lane * 2) = pk2(a[8] * inv, a[9] * inv);
}

// ---------------- dual gather, 4-deep X prefetch, shared x-read ----------------
__device__ __forceinline__ void gather_dual(const int* __restrict__ offs,
                                            const int* __restrict__ csr_src,
                                            const unsigned* __restrict__ wb,
                                            const bf16* __restrict__ X, int node,
                                            int lane, float* aa, float* ab) {
#pragma unroll
    for (int k = 0; k < KG; k++) { aa[k] = 0.0f; ab[k] = 0.0f; }
    int beg = rfl(offs[node]);
    int end = rfl(offs[node + 1]);
    int cnt = end - beg;
    int s4 = rfl(csr_src[clampe(beg + 4)]);
    float xv0 = ldxf(X, rfl(csr_src[clampe(beg + 0)]), lane);
    float xv1 = ldxf(X, rfl(csr_src[clampe(beg + 1)]), lane);
    float xv2 = ldxf(X, rfl(csr_src[clampe(beg + 2)]), lane);
    float xv3 = ldxf(X, rfl(csr_src[clampe(beg + 3)]), lane);
    const unsigned* wp0 = wb + (size_t)clampe(beg + 0) * 10;
    unsigned c0 = wp0[0], c1 = wp0[1], c2 = wp0[2], c3 = wp0[3], c4 = wp0[4];
    unsigned c5 = wp0[5], c6 = wp0[6], c7 = wp0[7], c8 = wp0[8], c9 = wp0[9];
    const unsigned* wp1 = wb + (size_t)clampe(beg + 1) * 10;
    unsigned n0 = wp1[0], n1 = wp1[1], n2 = wp1[2], n3 = wp1[3], n4 = wp1[4];
    unsigned n5 = wp1[5], n6 = wp1[6], n7 = wp1[7], n8 = wp1[8], n9 = wp1[9];
    for (int t = 0; t < cnt; ++t) {
        int s5 = rfl(csr_src[clampe(beg + t + 5)]);
        float xv4 = ldxf(X, s4, lane);                        // for t+4
        const unsigned* wp2 = wb + (size_t)clampe(beg + t + 2) * 10;
        unsigned m0 = wp2[0], m1 = wp2[1], m2 = wp2[2], m3 = wp2[3], m4 = wp2[4];
        unsigned m5 = wp2[5], m6 = wp2[6], m7 = wp2[7], m8 = wp2[8], m9 = wp2[9];
        aa[0] += blo(c0) * xv0; aa[1] += bhi(c0) * xv0;
        aa[2] += blo(c1) * xv0; aa[3] += bhi(c1) * xv0;
        aa[4] += blo(c2) * xv0; aa[5] += bhi(c2) * xv0;
        aa[6] += blo(c3) * xv0; aa[7] += bhi(c3) * xv0;
        aa[8] += blo(c4) * xv0; aa[9] += bhi(c4) * xv0;
        ab[0] += blo(c5) * xv0; ab[1] += bhi(c5) * xv0;
        ab[2] += blo(c6) * xv0; ab[3] += bhi(c6) * xv0;
        ab[4] += blo(c7) * xv0; ab[5] += bhi(c7) * xv0;
        ab[6] += blo(c8) * xv0; ab[7] += bhi(c8) * xv0;
        ab[8] += blo(c9) * xv0; ab[9] += bhi(c9) * xv0;
        xv0 = xv1; xv1 = xv2; xv2 = xv3; xv3 = xv4; s4 = s5;
        c0 = n0; c1 = n1; c2 = n2; c3 = n3; c4 = n4;
        c5 = n5; c6 = n6; c7 = n7; c8 = n8; c9 = n9;
        n0 = m0; n1 = m1; n2 = m2; n3 = m3; n4 = m4;
        n5 = m5; n6 = m6; n7 = m7; n8 = m8; n9 = m9;
    }
}

// ---------------- single gather, 4-deep X prefetch ----------------
__device__ __forceinline__ void gather_one(const int* __restrict__ offs,
                                           const int* __restrict__ csr_src,
                                           const unsigned* __restrict__ wb,
                                           const bf16* __restrict__ X, int node,
                                           int lane, float* acc) {
#pragma unroll
    for (int k = 0; k < KG; k++) acc[k] = 0.0f;
    int beg = rfl(offs[node]);
    int end = rfl(offs[node + 1]);
    int cnt = end - beg;
    int s4 = rfl(csr_src[clampe(beg + 4)]);
    float xv0 = ldxf(X, rfl(csr_src[clampe(beg + 0)]), lane);
    float xv1 = ldxf(X, rfl(csr_src[clampe(beg + 1)]), lane);
    float xv2 = ldxf(X, rfl(csr_src[clampe(beg + 2)]), lane);
    float xv3 = ldxf(X, rfl(csr_src[clampe(beg + 3)]), lane);
    const unsigned* wp0 = wb + (size_t)clampe(beg + 0) * 5;
    unsigned c0 = wp0[0], c1 = wp0[1], c2 = wp0[2], c3 = wp0[3], c4 = wp0[4];
    const unsigned* wp1 = wb + (size_t)clampe(beg + 1) * 5;
    unsigned n0 = wp1[0], n1 = wp1[1], n2 = wp1[2], n3 = wp1[3], n4 = wp1[4];
    for (int t = 0; t < cnt; ++t) {
        int s5 = rfl(csr_src[clampe(beg + t + 5)]);
        float xv4 = ldxf(X, s4, lane);                        // for t+4
        const unsigned* wp2 = wb + (size_t)clampe(beg + t + 2) * 5;
        unsigned m0 = wp2[0], m1 = wp2[1], m2 = wp2[2], m3 = wp2[3], m4 = wp2[4];
        acc[0] += blo(c0) * xv0; acc[1] += bhi(c0) * xv0;
        acc[2] += blo(c1) * xv0; acc[3] += bhi(c1) * xv0;
        acc[4] += blo(c2) * xv0; acc[5] += bhi(c2) * xv0;
        acc[6] += blo(c3) * xv0; acc[7] += bhi(c3) * xv0;
        acc[8] += blo(c4) * xv0; acc[9] += bhi(c4) * xv0;
        xv0 = xv1; xv1 = xv2; xv2 = xv3; xv3 = xv4; s4 = s5;
        c0 = n0; c1 = n1; c2 = n2; c3 = n3; c4 = n4;
        n0 = m0; n1 = m1; n2 = m2; n3 = m3; n4 = m4;
    }
}

// ---------------- fusedA: dual gather(x;w1,ws) -> z1,zs; conv1 GEMM -> hf,
//                  shortcut GEMM -> ys (+bs, no relu) ----------------
__global__ __launch_bounds__(512) void k_fusedA(
    const int* __restrict__ offs, const int* __restrict__ csr_src,
    const bf16* __restrict__ wcab, const float* __restrict__ invdeg,
    const bf16* __restrict__ Xf, const bf16* __restrict__ wt1p,
    const bf16* __restrict__ wtsp, const void* __restrict__ b1,
    const void* __restrict__ bs, const int* __restrict__ flag,
    bf16* __restrict__ hf, bf16* __restrict__ ys) {
    __shared__ bf16 z1[ZT];
    __shared__ bf16 zs[ZT];
    int lane = threadIdx.x & 63;
    int wave = threadIdx.x >> 6;
    int bid = blockIdx.x;

#pragma unroll
    for (int i = 0; i < 2; i++) {
        int r = wave * 2 + i;
        int node = bid * 16 + r;
        float aa[KG], ab[KG];
        gather_dual(offs, csr_src, (const unsigned*)wcab, Xf, node, lane, aa, ab);
        float inv = invdeg[node];
        store_zlds(z1, r, lane, aa, inv);
        store_zlds(zs, r, lane, ab, inv);
    }
    __syncthreads();

    int m = lane & 15, quad = lane >> 4;
    int row0 = bid * 16;
    int f = flag[0];

    // shortcut GEMM: col-tile n = wave (Cout=128), -> ys row-major (+bs)
    {
        float4v acc4 = (float4v){0.f, 0.f, 0.f, 0.f};
        const bf16* brow = wtsp + ((size_t)(wave * 22) * 64 + lane) * 8;
        const bf16* xrow = Xf + (size_t)(row0 + m) * 64;
#pragma unroll
        for (int kc = 0; kc < 22; kc++) {
            short8 a = (kc < 20)
                ? *(const short8*)(zs + m * ZRS + kc * 32 + quad * 8)
                : *(const short8*)(xrow + (kc - 20) * 32 + quad * 8);
            short8 b = *(const short8*)(brow + (size_t)kc * 512);
            acc4 = __builtin_amdgcn_mfma_f32_16x16x32_bf16(a, b, acc4, 0, 0, 0);
        }
        int gcol = wave * 16 + m;
        float bv = ldf(bs, gcol, f);
#pragma unroll
        for (int r = 0; r < 4; r++) {
            int grow = row0 + quad * 4 + r;
            if (grow >= N_NODES) continue;
            ys[(size_t)grow * 128 + gcol] = __float2bfloat16(acc4[r] + bv);
        }
    }

    // conv1 GEMM (waves 0-3): col-tile n = wave (Cout=64), -> hf (relu)
    if (wave < 4) {
        float4v acc4 = (float4v){0.f, 0.f, 0.f, 0.f};
        const bf16* brow = wt1p + ((size_t)(wave * 22) * 64 + lane) * 8;
        const bf16* xrow = Xf + (size_t)(row0 + m) * 64;
#pragma unroll
        for (int kc = 0; kc < 22; kc++) {
            short8 a = (kc < 20)
                ? *(const short8*)(z1 + m * ZRS + kc * 32 + quad * 8)
                : *(const short8*)(xrow + (kc - 20) * 32 + quad * 8);
            short8 b = *(const short8*)(brow + (size_t)kc * 512);
            acc4 = __builtin_amdgcn_mfma_f32_16x16x32_bf16(a, b, acc4, 0, 0, 0);
        }
        int gcol = wave * 16 + m;
        float bv = ldf(b1, gcol, f);
#pragma unroll
        for (int r = 0; r < 4; r++) {
            int grow = row0 + quad * 4 + r;
            if (grow >= N_NODES) continue;
            float v = fmaxf(acc4[r] + bv, 0.f);
            hf[(size_t)grow * 64 + gcol] = __float2bfloat16(v);
        }
    }
}

// ---------------- fusedB: gather(hf;w2) -> z; conv2 GEMM + ys + relu -> out -----
__global__ __launch_bounds__(512) void k_fusedB(
    const int* __restrict__ offs, const int* __restrict__ csr_src,
    const bf16* __restrict__ wc2, const float* __restrict__ invdeg,
    const bf16* __restrict__ hf, const bf16* __restrict__ wt2p,
    const void* __restrict__ b2, const bf16* __restrict__ ys,
    const int* __restrict__ flag, void* __restrict__ out) {
    __shared__ bf16 z[ZT];
    int lane = threadIdx.x & 63;
    int wave = threadIdx.x >> 6;
    int bid = blockIdx.x;

#pragma unroll
    for (int i = 0; i < 2; i++) {
        int r = wave * 2 + i;
        int node = bid * 16 + r;
        float acc[KG];
        gather_one(offs, csr_src, (const unsigned*)wc2, hf, node, lane, acc);
        store_zlds(z, r, lane, acc, invdeg[node]);
    }
    __syncthreads();

    int m = lane & 15, quad = lane >> 4;
    int row0 = bid * 16;
    int f = flag[0];
    float4v acc4 = (float4v){0.f, 0.f, 0.f, 0.f};
    const bf16* brow = wt2p + ((size_t)(wave * 22) * 64 + lane) * 8;
    const bf16* hrow = hf + (size_t)(row0 + m) * 64;
#pragma unroll
    for (int kc = 0; kc < 22; kc++) {
        short8 a = (kc < 20)
            ? *(const short8*)(z + m * ZRS + kc * 32 + quad * 8)
            : *(const short8*)(hrow + (kc - 20) * 32 + quad * 8);
        short8 b = *(const short8*)(brow + (size_t)kc * 512);
        acc4 = __builtin_amdgcn_mfma_f32_16x16x32_bf16(a, b, acc4, 0, 0, 0);
    }
    int gcol = wave * 16 + m;
    float bv = ldf(b2, gcol, f);
#pragma unroll
    for (int r = 0; r < 4; r++) {
        int grow = row0 + quad * 4 + r;
        if (grow >= N_NODES) continue;
        size_t oidx = (size_t)grow * 128 + gcol;
        float v = fmaxf(acc4[r] + bv + __bfloat162float(ys[oidx]), 0.f);
        if (f) ((float*)out)[oidx] = v;
        else   ((bf16*)out)[oidx] = __float2bfloat16(v);
    }
}

extern "C" void kernel_launch(void* const* d_in, const int* in_sizes, int n_in,
                              void* d_out, int out_size, void* d_ws, size_t ws_size,
                              hipStream_t stream) {
    const void* x      = d_in[0];
    const int*  ei     = (const int*)d_in[1];
    const void* pseudo = d_in[2];
    const void* g1     = d_in[3];
    const void* mu1    = d_in[4];
    const void* sg1    = d_in[5];
    const void* root1  = d_in[6];
    const void* b1     = d_in[7];
    const void* g2     = d_in[8];
    const void* mu2    = d_in[9];
    const void* sg2    = d_in[10];
    const void* root2  = d_in[11];
    const void* b2     = d_in[12];
    const void* gs     = d_in[13];
    const void* mus    = d_in[14];
    const void* sgs    = d_in[15];
    const void* roots  = d_in[16];
    const void* bs     = d_in[17];

    char* ws = (char*)d_ws;
    size_t off = 0;
    auto alloc = [&](size_t bytes) -> char* {
        char* p = ws + off;
        off += (bytes + 255) & ~(size_t)255;
        return p;
    };
    const size_t XFS = (size_t)NP * 64 * 2;          // 5.25 MB node-contig x/h

    int*   flag   = (int*)alloc(256);
    int*   deg    = (int*)alloc((size_t)NP * 4);
    int*   offs   = (int*)alloc((size_t)(NP + 1) * 4);
    int*   cur    = (int*)alloc((size_t)NP * 4);
    float* invdeg = (float*)alloc((size_t)NP * 4);
    int*   bsum   = (int*)alloc((size_t)NBLK * 4);
    int*   ep     = (int*)alloc((size_t)N_EDGES * 4);
    int*   csrs   = (int*)alloc((size_t)N_EDGES * 4);
    bf16*  Xf     = (bf16*)alloc(XFS);
    bf16*  hf     = (bf16*)alloc(XFS);
    bf16*  ys     = (bf16*)alloc((size_t)NP * 128 * 2);
    bf16*  wt1p   = (bf16*)alloc((size_t)64 * 704 * 2);
    bf16*  wt2p   = (bf16*)alloc((size_t)128 * 704 * 2);
    bf16*  wtsp   = (bf16*)alloc((size_t)128 * 704 * 2);
    bf16*  wcab   = (bf16*)alloc((size_t)N_EDGES * 20 * 2);   // {w1, ws} csr-order
    bf16*  wc2    = (bf16*)alloc((size_t)N_EDGES * 10 * 2);   // w2 csr-order
    (void)ws_size;

    hipMemsetAsync(deg, 0, (size_t)NP * 4, stream);
    k_detect_count<<<1 + (N_EDGES + 255) / 256, 256, 0, stream>>>(x, ei, flag, deg);
    k_scan1<<<NBLK, SCAN_B, 0, stream>>>(deg, offs, bsum);
    k_scan3m<<<NBLK, 256, 0, stream>>>(offs, bsum, deg, cur, invdeg);
    k_fill<<<(N_EDGES + 255) / 256, 256, 0, stream>>>(ei, cur, ep, csrs);
    k_prep_all<<<CVT_BLK + W3_BLK + PACK_BLK, 256, 0, stream>>>(
        x, pseudo, mu1, sg1, mu2, sg2, mus, sgs, g1, root1, g2, root2, gs, roots,
        flag, ep, Xf, wcab, wc2, wt1p, wt2p, wtsp);
    k_fusedA<<<GRIDF, 512, 0, stream>>>(offs, csrs, wcab, invdeg, Xf, wt1p, wtsp,
                                        b1, bs, flag, hf, ys);
    k_fusedB<<<GRIDF, 512, 0, stream>>>(offs, csrs, wc2, invdeg, hf, wt2p, b2,
                                        ys, flag, d_out);
}